// Round 2
// 355.023 us; speedup vs baseline: 1.0306x; 1.0306x over previous
//
#include <hip/hip_runtime.h>

// PolyPoolerTextLenSensitive — MI355X (gfx950)
//
// Inputs (setup_inputs order):
//   d_in[0] feat0  (2,256,200,336) f32
//   d_in[1] feat1  (2,256,100,168) f32
//   d_in[2] feat2  (2,256, 50, 84) f32
//   d_in[3] feat3  (2,256, 25, 42) f32
//   d_in[4] polys  (256,14,2)      f32
//   d_in[5] img_ids(256,)          i32
//   d_in[6] lens   (256,)          i32
// Output: out0 (256,256,8,32) then out1 (256,256,8,64), f32, concat flat.
//
// R1 changes vs 127.4 µs baseline (theory: latency-serialized gathers, MLP≈4):
//  - channel loop unrolled 8x (pid0) / 4x (pid1) with explicit load-phase
//    arrays -> 32 gathers in flight per wave before first dependent FMA
//  - zero-fill path: 16B non-temporal stores (native vector type — HIP float4
//    is a class and __builtin_nontemporal_store rejects it)
//  - geometry computed straight into registers (soff/swt LDS round-trip and
//    2 of 3 __syncthreads removed; only 28-float pts broadcast remains)
//  - non-temporal output stores (201 MB stream, never re-read, > L2)

#define NBOX 256
#define NCH  256
#define HP   8
#define CCHUNK 32
#define OUT0_ELEMS ((size_t)NBOX * NCH * HP * 32)

typedef float f32x4 __attribute__((ext_vector_type(4)));

__device__ __forceinline__ void make_geo(
    const float* __restrict__ pts, int pos, int lwp, int W, int H,
    int& o00, int& o10, int& o01, int& o11,
    float& w00, float& w10, float& w01, float& w11)
{
    const int wp = 1 << lwp;
    const int i  = pos >> lwp;
    const int j  = pos & (wp - 1);

    // boundary interp parameter (n-1 = 6 segments)
    float u  = ((j + 0.5f) / (float)wp) * 6.0f;
    int   i0 = (int)floorf(u);
    i0 = min(max(i0, 0), 5);
    float f = u - (float)i0;

    // top points: polys[b, i0], polys[b, i0+1] normalized by (1344, 800)
    float txa = pts[2 * i0]     / 1344.0f, tya = pts[2 * i0 + 1] / 800.0f;
    float txb = pts[2 * i0 + 2] / 1344.0f, tyb = pts[2 * i0 + 3] / 800.0f;
    // bottom points (reversed): pn[7+m] = polys[b, 13-m]
    int ka = 13 - i0, kb = 12 - i0;
    float bxa = pts[2 * ka] / 1344.0f, bya = pts[2 * ka + 1] / 800.0f;
    float bxb = pts[2 * kb] / 1344.0f, byb = pts[2 * kb + 1] / 800.0f;

    float topx = txa * (1.0f - f) + txb * f;
    float topy = tya * (1.0f - f) + tyb * f;
    float botx = bxa * (1.0f - f) + bxb * f;
    float boty = bya * (1.0f - f) + byb * f;

    float v  = (i + 0.5f) / 8.0f;
    float gx = topx * (1.0f - v) + botx * v;
    float gy = topy * (1.0f - v) + boty * v;

    float x = gx * (float)W - 0.5f;
    float y = gy * (float)H - 0.5f;
    float x0f = floorf(x), y0f = floorf(y);
    float fx = x - x0f,   fy = y - y0f;
    int x0 = (int)x0f, y0 = (int)y0f;
    int x1 = x0 + 1,   y1 = y0 + 1;

    int x0c = min(max(x0, 0), W - 1), x1c = min(max(x1, 0), W - 1);
    int y0c = min(max(y0, 0), H - 1), y1c = min(max(y1, 0), H - 1);
    float m00 = (x0 >= 0 && x0 < W && y0 >= 0 && y0 < H) ? 1.0f : 0.0f;
    float m10 = (x1 >= 0 && x1 < W && y0 >= 0 && y0 < H) ? 1.0f : 0.0f;
    float m01 = (x0 >= 0 && x0 < W && y1 >= 0 && y1 < H) ? 1.0f : 0.0f;
    float m11 = (x1 >= 0 && x1 < W && y1 >= 0 && y1 < H) ? 1.0f : 0.0f;

    o00 = y0c * W + x0c;  o10 = y0c * W + x1c;
    o01 = y1c * W + x0c;  o11 = y1c * W + x1c;
    w00 = (1.0f - fx) * (1.0f - fy) * m00;
    w10 = fx * (1.0f - fy) * m10;
    w01 = (1.0f - fx) * fy * m01;
    w11 = fx * fy * m11;
}

__global__ __launch_bounds__(256) void poly_pool_kernel(
    const float* __restrict__ f0, const float* __restrict__ f1,
    const float* __restrict__ f2, const float* __restrict__ f3,
    const float* __restrict__ polys, const int* __restrict__ img_ids,
    const int* __restrict__ lens, float* __restrict__ out)
{
    const int b    = blockIdx.y;
    const int pidk = blockIdx.z;            // 0 -> (8,32), 1 -> (8,64)
    const int lwp  = 5 + pidk;
    const int npos = HP << lwp;             // 256 or 512
    const int c0   = blockIdx.x * CCHUNK;
    const int tid  = threadIdx.x;

    float* outb = out + (pidk ? OUT0_ELEMS : (size_t)0) + (size_t)b * NCH * npos;

    // pooler routing: pooler_id = (lens > 8)
    const int pooler = (lens[b] > 8) ? 1 : 0;
    if (pooler != pidk) {
        // this box contributes zeros to this output tensor — 16B nt stores
        f32x4 z = (f32x4)(0.0f);
        f32x4* p = reinterpret_cast<f32x4*>(outb + (size_t)c0 * npos);
        const int total4 = (CCHUNK * npos) >> 2;   // 2048 or 4096
        for (int k = tid; k < total4; k += 256)
            __builtin_nontemporal_store(z, p + k);
        return;
    }

    __shared__ float pts[28];               // polys[b] : 14 points x 2
    if (tid < 28) pts[tid] = polys[b * 28 + tid];
    __syncthreads();

    // ---- level selection: s = sqrt(dx*dy) over raw points ----
    float minx = pts[0], maxx = pts[0], miny = pts[1], maxy = pts[1];
#pragma unroll
    for (int k = 1; k < 14; ++k) {
        float x = pts[2 * k], y = pts[2 * k + 1];
        minx = fminf(minx, x); maxx = fmaxf(maxx, x);
        miny = fminf(miny, y); maxy = fmaxf(maxy, y);
    }
    float s = sqrtf((maxx - minx) * (maxy - miny));
    int lvl = (int)floorf(4.0f + log2f(s / 224.0f + 1e-6f));
    lvl = min(max(lvl, 2), 5) - 2;

    const float* feat; int H, W;
    switch (lvl) {
        case 0:  feat = f0; H = 200; W = 336; break;
        case 1:  feat = f1; H = 100; W = 168; break;
        case 2:  feat = f2; H = 50;  W = 84;  break;
        default: feat = f3; H = 25;  W = 42;  break;
    }
    const int img = img_ids[b];
    const int HW  = H * W;
    const float* featimg = feat + (size_t)img * NCH * HW;
    const float* fbase   = featimg + (size_t)c0 * HW;

    // ---- geometry straight into registers (pos = tid, and tid+256 if wp=64)
    int   o00, o10, o01, o11;
    float w00, w10, w01, w11;
    make_geo(pts, tid, lwp, W, H, o00, o10, o01, o11, w00, w10, w01, w11);

    float* op = outb + (size_t)c0 * npos + tid;

    if (!pidk) {
        // 256 positions, 1 per thread. Unroll 8 channels: 32 loads in flight.
        for (int c = 0; c < CCHUNK; c += 8) {
            float t00[8], t10[8], t01[8], t11[8];
#pragma unroll
            for (int k = 0; k < 8; ++k) {
                const float* fc = fbase + (size_t)(c + k) * HW;
                t00[k] = fc[o00]; t10[k] = fc[o10];
                t01[k] = fc[o01]; t11[k] = fc[o11];
            }
#pragma unroll
            for (int k = 0; k < 8; ++k) {
                float r = w00 * t00[k] + w10 * t10[k] + w01 * t01[k] + w11 * t11[k];
                __builtin_nontemporal_store(r, op + (size_t)(c + k) * 256);
            }
        }
    } else {
        // 512 positions, 2 per thread. Unroll 4 channels: 32 loads in flight.
        int   q00, q10, q01, q11;
        float v00, v10, v01, v11;
        make_geo(pts, tid + 256, lwp, W, H, q00, q10, q01, q11, v00, v10, v01, v11);

        for (int c = 0; c < CCHUNK; c += 4) {
            float t00[4], t10[4], t01[4], t11[4];
            float s00[4], s10[4], s01[4], s11[4];
#pragma unroll
            for (int k = 0; k < 4; ++k) {
                const float* fc = fbase + (size_t)(c + k) * HW;
                t00[k] = fc[o00]; t10[k] = fc[o10];
                t01[k] = fc[o01]; t11[k] = fc[o11];
                s00[k] = fc[q00]; s10[k] = fc[q10];
                s01[k] = fc[q01]; s11[k] = fc[q11];
            }
#pragma unroll
            for (int k = 0; k < 4; ++k) {
                float r0 = w00 * t00[k] + w10 * t10[k] + w01 * t01[k] + w11 * t11[k];
                float r1 = v00 * s00[k] + v10 * s10[k] + v01 * s01[k] + v11 * s11[k];
                __builtin_nontemporal_store(r0, op + (size_t)(c + k) * 512);
                __builtin_nontemporal_store(r1, op + (size_t)(c + k) * 512 + 256);
            }
        }
    }
}

extern "C" void kernel_launch(void* const* d_in, const int* in_sizes, int n_in,
                              void* d_out, int out_size, void* d_ws, size_t ws_size,
                              hipStream_t stream) {
    const float* f0    = (const float*)d_in[0];
    const float* f1    = (const float*)d_in[1];
    const float* f2    = (const float*)d_in[2];
    const float* f3    = (const float*)d_in[3];
    const float* polys = (const float*)d_in[4];
    const int*   ids   = (const int*)d_in[5];
    const int*   lens  = (const int*)d_in[6];
    float* out = (float*)d_out;

    dim3 grid(NCH / CCHUNK, NBOX, 2);   // (8, 256, 2)
    poly_pool_kernel<<<grid, 256, 0, stream>>>(f0, f1, f2, f3, polys, ids, lens, out);
}

// Round 3
// 343.993 us; speedup vs baseline: 1.0636x; 1.0321x over previous
//
#include <hip/hip_runtime.h>

// PolyPoolerTextLenSensitive — MI355X (gfx950)
//
// Inputs (setup_inputs order):
//   d_in[0] feat0  (2,256,200,336) f32
//   d_in[1] feat1  (2,256,100,168) f32
//   d_in[2] feat2  (2,256, 50, 84) f32
//   d_in[3] feat3  (2,256, 25, 42) f32
//   d_in[4] polys  (256,14,2)      f32
//   d_in[5] img_ids(256,)          i32
//   d_in[6] lens   (256,)          i32
// Output: out0 (256,256,8,32) then out1 (256,256,8,64), f32, concat flat.
//
// R2: LDS patch staging. R1 post-mortem showed ILP alone bought ~10% —
// bottleneck is divergent-VMEM gather throughput, not latency. Canonical
// level selection bounds each box's footprint in its feature level to
// ~<=1400 px (~5.6 KB/ch), so we stage per-channel patches in LDS
// (coalesced row loads, power-of-2 padded stride -> shift indexing) and
// do the 4 bilinear taps as ds_read_b32. Uniform fallback to direct
// gather if a patch ever exceeds the cap.

#define NBOX 256
#define NCH  256
#define HP   8
#define CCHUNK 32
#define NSTG 4
#define PMAX 2560              // floats per staged channel patch (10 KB)
#define OUT0_ELEMS ((size_t)NBOX * NCH * HP * 32)

typedef float f32x4 __attribute__((ext_vector_type(4)));

// Bilinear geometry for one grid position: clamped corner coords + weights.
__device__ __forceinline__ void make_geo(
    const float* __restrict__ pts, int pos, int lwp, int W, int H,
    int& x0c, int& x1c, int& y0c, int& y1c,
    float& w00, float& w10, float& w01, float& w11)
{
    const int wp = 1 << lwp;
    const int i  = pos >> lwp;
    const int j  = pos & (wp - 1);

    // boundary interp parameter (n-1 = 6 segments)
    float u  = ((j + 0.5f) / (float)wp) * 6.0f;
    int   i0 = (int)floorf(u);
    i0 = min(max(i0, 0), 5);
    float f = u - (float)i0;

    // top points: polys[b, i0], polys[b, i0+1] normalized by (1344, 800)
    float txa = pts[2 * i0]     / 1344.0f, tya = pts[2 * i0 + 1] / 800.0f;
    float txb = pts[2 * i0 + 2] / 1344.0f, tyb = pts[2 * i0 + 3] / 800.0f;
    // bottom points (reversed): pn[7+m] = polys[b, 13-m]
    int ka = 13 - i0, kb = 12 - i0;
    float bxa = pts[2 * ka] / 1344.0f, bya = pts[2 * ka + 1] / 800.0f;
    float bxb = pts[2 * kb] / 1344.0f, byb = pts[2 * kb + 1] / 800.0f;

    float topx = txa * (1.0f - f) + txb * f;
    float topy = tya * (1.0f - f) + tyb * f;
    float botx = bxa * (1.0f - f) + bxb * f;
    float boty = bya * (1.0f - f) + byb * f;

    float v  = (i + 0.5f) / 8.0f;
    float gx = topx * (1.0f - v) + botx * v;
    float gy = topy * (1.0f - v) + boty * v;

    float x = gx * (float)W - 0.5f;
    float y = gy * (float)H - 0.5f;
    float x0f = floorf(x), y0f = floorf(y);
    float fx = x - x0f,   fy = y - y0f;
    int x0 = (int)x0f, y0 = (int)y0f;
    int x1 = x0 + 1,   y1 = y0 + 1;

    x0c = min(max(x0, 0), W - 1); x1c = min(max(x1, 0), W - 1);
    y0c = min(max(y0, 0), H - 1); y1c = min(max(y1, 0), H - 1);
    float m00 = (x0 >= 0 && x0 < W && y0 >= 0 && y0 < H) ? 1.0f : 0.0f;
    float m10 = (x1 >= 0 && x1 < W && y0 >= 0 && y0 < H) ? 1.0f : 0.0f;
    float m01 = (x0 >= 0 && x0 < W && y1 >= 0 && y1 < H) ? 1.0f : 0.0f;
    float m11 = (x1 >= 0 && x1 < W && y1 >= 0 && y1 < H) ? 1.0f : 0.0f;

    w00 = (1.0f - fx) * (1.0f - fy) * m00;
    w10 = fx * (1.0f - fy) * m10;
    w01 = (1.0f - fx) * fy * m01;
    w11 = fx * fy * m11;
}

__global__ __launch_bounds__(256) void poly_pool_kernel(
    const float* __restrict__ f0, const float* __restrict__ f1,
    const float* __restrict__ f2, const float* __restrict__ f3,
    const float* __restrict__ polys, const int* __restrict__ img_ids,
    const int* __restrict__ lens, float* __restrict__ out)
{
    const int b    = blockIdx.y;
    const int pidk = blockIdx.z;            // 0 -> (8,32), 1 -> (8,64)
    const int lwp  = 5 + pidk;
    const int npos = HP << lwp;             // 256 or 512
    const int c0   = blockIdx.x * CCHUNK;
    const int tid  = threadIdx.x;

    float* outb = out + (pidk ? OUT0_ELEMS : (size_t)0) + (size_t)b * NCH * npos;

    // pooler routing: pooler_id = (lens > 8)
    const int pooler = (lens[b] > 8) ? 1 : 0;
    if (pooler != pidk) {
        // this box contributes zeros to this output tensor — 16B nt stores
        f32x4 z = (f32x4)(0.0f);
        f32x4* p = reinterpret_cast<f32x4*>(outb + (size_t)c0 * npos);
        const int total4 = (CCHUNK * npos) >> 2;   // 2048 or 4096
        for (int k = tid; k < total4; k += 256)
            __builtin_nontemporal_store(z, p + k);
        return;
    }

    __shared__ float pts[28];               // polys[b] : 14 points x 2
    __shared__ float patch[NSTG][PMAX];     // 40 KB staging
    if (tid < 28) pts[tid] = polys[b * 28 + tid];
    __syncthreads();

    // ---- level selection: s = sqrt(dx*dy) over raw points ----
    float minx = pts[0], maxx = pts[0], miny = pts[1], maxy = pts[1];
#pragma unroll
    for (int k = 1; k < 14; ++k) {
        float x = pts[2 * k], y = pts[2 * k + 1];
        minx = fminf(minx, x); maxx = fmaxf(maxx, x);
        miny = fminf(miny, y); maxy = fmaxf(maxy, y);
    }
    float s = sqrtf((maxx - minx) * (maxy - miny));
    int lvl = (int)floorf(4.0f + log2f(s / 224.0f + 1e-6f));
    lvl = min(max(lvl, 2), 5) - 2;

    const float* feat; int H, W;
    switch (lvl) {
        case 0:  feat = f0; H = 200; W = 336; break;
        case 1:  feat = f1; H = 100; W = 168; break;
        case 2:  feat = f2; H = 50;  W = 84;  break;
        default: feat = f3; H = 25;  W = 42;  break;
    }
    const int img = img_ids[b];
    const int HW  = H * W;
    const float* featimg = feat + (size_t)img * NCH * HW;

    // ---- patch bounding box in feature coords (grid is convex in poly pts)
    float sxn = (float)W / 1344.0f, syn = (float)H / 800.0f;
    int px0 = min(max((int)floorf(minx * sxn - 0.5f), 0), W - 1);
    int px1 = min(max((int)floorf(maxx * sxn - 0.5f) + 1, 0), W - 1);
    int py0 = min(max((int)floorf(miny * syn - 0.5f), 0), H - 1);
    int py1 = min(max((int)floorf(maxy * syn - 0.5f) + 1, 0), H - 1);
    const int PW = px1 - px0 + 1;
    const int PH = py1 - py0 + 1;
    const int lg = (PW <= 64) ? 6 : ((PW <= 128) ? 7 : 8);
    const int PWP = 1 << lg;
    const int npatch = PH << lg;
    const bool staged = (PW <= 256) && (npatch <= PMAX);  // uniform per block

    // ---- geometry in registers (pos = tid, and tid+256 if wp=64) ----
    int   x0c, x1c, y0c, y1c;
    float w00, w10, w01, w11;
    make_geo(pts, tid, lwp, W, H, x0c, x1c, y0c, y1c, w00, w10, w01, w11);
    int   x0d = 0, x1d = 0, y0d = 0, y1d = 0;
    float v00 = 0, v10 = 0, v01 = 0, v11 = 0;
    if (pidk)
        make_geo(pts, tid + 256, lwp, W, H, x0d, x1d, y0d, y1d, v00, v10, v01, v11);

    float* op = outb + (size_t)c0 * npos + tid;

    if (staged) {
        // LDS-local tap offsets (row stride PWP, shift-indexed)
        const int o00 = ((y0c - py0) << lg) + (x0c - px0);
        const int o10 = ((y0c - py0) << lg) + (x1c - px0);
        const int o01 = ((y1c - py0) << lg) + (x0c - px0);
        const int o11 = ((y1c - py0) << lg) + (x1c - px0);
        int q00 = 0, q10 = 0, q01 = 0, q11 = 0;
        if (pidk) {
            q00 = ((y0d - py0) << lg) + (x0d - px0);
            q10 = ((y0d - py0) << lg) + (x1d - px0);
            q01 = ((y1d - py0) << lg) + (x0d - px0);
            q11 = ((y1d - py0) << lg) + (x1d - px0);
        }

        for (int rnd = 0; rnd < CCHUNK / NSTG; ++rnd) {
            // ---- cooperative, coalesced staging of NSTG channel patches ----
            const float* sb = featimg + (size_t)(c0 + rnd * NSTG) * HW
                              + (size_t)py0 * W + px0;
            for (int e = tid; e < npatch; e += 512) {
                int eb = min(e + 256, npatch - 1);
                int ra = e  >> lg, ca = min(e  & (PWP - 1), PW - 1);
                int rb = eb >> lg, cb = min(eb & (PWP - 1), PW - 1);
                const float* sA = sb + ra * W + ca;
                const float* sB = sb + rb * W + cb;
                // 8 independent loads in flight, then 8 LDS writes
                float a0 = sA[0], a1 = sA[HW], a2 = sA[2 * HW], a3 = sA[3 * HW];
                float b0 = sB[0], b1 = sB[HW], b2 = sB[2 * HW], b3 = sB[3 * HW];
                patch[0][e]  = a0; patch[1][e]  = a1;
                patch[2][e]  = a2; patch[3][e]  = a3;
                patch[0][eb] = b0; patch[1][eb] = b1;
                patch[2][eb] = b2; patch[3][eb] = b3;
            }
            __syncthreads();

            // ---- bilinear taps from LDS ----
#pragma unroll
            for (int k = 0; k < NSTG; ++k) {
                float r0 = w00 * patch[k][o00] + w10 * patch[k][o10]
                         + w01 * patch[k][o01] + w11 * patch[k][o11];
                __builtin_nontemporal_store(r0, op + (size_t)(rnd * NSTG + k) * npos);
            }
            if (pidk) {
#pragma unroll
                for (int k = 0; k < NSTG; ++k) {
                    float r1 = v00 * patch[k][q00] + v10 * patch[k][q10]
                             + v01 * patch[k][q01] + v11 * patch[k][q11];
                    __builtin_nontemporal_store(r1, op + (size_t)(rnd * NSTG + k) * npos + 256);
                }
            }
            __syncthreads();
        }
    } else {
        // ---- fallback: direct global gather (uniform branch; not expected
        //      to trigger for this input distribution, kept for correctness)
        const int g00 = y0c * W + x0c, g10 = y0c * W + x1c;
        const int g01 = y1c * W + x0c, g11 = y1c * W + x1c;
        int h00 = 0, h10 = 0, h01 = 0, h11 = 0;
        if (pidk) {
            h00 = y0d * W + x0d; h10 = y0d * W + x1d;
            h01 = y1d * W + x0d; h11 = y1d * W + x1d;
        }
        const float* fb = featimg + (size_t)c0 * HW;
        for (int c = 0; c < CCHUNK; ++c) {
            const float* fc = fb + (size_t)c * HW;
            float r0 = w00 * fc[g00] + w10 * fc[g10] + w01 * fc[g01] + w11 * fc[g11];
            __builtin_nontemporal_store(r0, op + (size_t)c * npos);
            if (pidk) {
                float r1 = v00 * fc[h00] + v10 * fc[h10] + v01 * fc[h01] + v11 * fc[h11];
                __builtin_nontemporal_store(r1, op + (size_t)c * npos + 256);
            }
        }
    }
}

extern "C" void kernel_launch(void* const* d_in, const int* in_sizes, int n_in,
                              void* d_out, int out_size, void* d_ws, size_t ws_size,
                              hipStream_t stream) {
    const float* f0    = (const float*)d_in[0];
    const float* f1    = (const float*)d_in[1];
    const float* f2    = (const float*)d_in[2];
    const float* f3    = (const float*)d_in[3];
    const float* polys = (const float*)d_in[4];
    const int*   ids   = (const int*)d_in[5];
    const int*   lens  = (const int*)d_in[6];
    float* out = (float*)d_out;

    dim3 grid(NCH / CCHUNK, NBOX, 2);   // (8, 256, 2)
    poly_pool_kernel<<<grid, 256, 0, stream>>>(f0, f1, f2, f3, polys, ids, lens, out);
}